// Round 3
// baseline (401.404 us; speedup 1.0000x reference)
//
#include <hip/hip_runtime.h>

#define NDIM 32
#define RPB 128            // rows per bucket
#define RPB_SHIFT 7
#define MAXB 1024          // max buckets supported (N <= 131072)
#define COL_BITS 17
#define SCAT_EPT 32        // edges per thread in scatter
#define SCAT_BLOCK 256
#define SCAT_CHUNK (SCAT_EPT * SCAT_BLOCK)   // 8192

// ---------- pass 0: global bucket histogram (per-WG LDS hist, merged) ----------
__global__ void k_bhist(const int* __restrict__ rows, int* __restrict__ ghist,
                        int n_edges, int nbuck) {
    __shared__ int h[MAXB];
    for (int b = threadIdx.x; b < nbuck; b += blockDim.x) h[b] = 0;
    __syncthreads();
    int stride = gridDim.x * blockDim.x;
    for (int e = blockIdx.x * blockDim.x + threadIdx.x; e < n_edges; e += stride)
        atomicAdd(&h[rows[e] >> RPB_SHIFT], 1);
    __syncthreads();
    for (int b = threadIdx.x; b < nbuck; b += blockDim.x)
        if (h[b]) atomicAdd(&ghist[b], h[b]);
}

// ---------- pass 1: exclusive scan of bucket counts (1 WG, nbuck <= 1024) ----------
__global__ void k_bscan(const int* __restrict__ ghist, int* __restrict__ starts,
                        int* __restrict__ cursor, int nbuck) {
    __shared__ int lds[MAXB];
    int t = threadIdx.x;
    int v = (t < nbuck) ? ghist[t] : 0;
    lds[t] = v;
    __syncthreads();
    for (int off = 1; off < MAXB; off <<= 1) {
        int x = (t >= off) ? lds[t - off] : 0;
        __syncthreads();
        if (t >= off) lds[t] += x;
        __syncthreads();
    }
    int excl = lds[t] - v;
    if (t < nbuck) { starts[t] = excl; cursor[t] = excl; }
    if (t == nbuck - 1) starts[nbuck] = lds[t];
}

// ---------- pass 2: chunked rank-and-place into bucket order ----------
__global__ void k_bscatter(const int* __restrict__ rows, const int* __restrict__ cols,
                           const float* __restrict__ vals, int* __restrict__ gcursor,
                           int2* __restrict__ edges, int n_edges, int nbuck) {
    __shared__ int h[MAXB];
    __shared__ int cur[MAXB];
    long long base = (long long)blockIdx.x * SCAT_CHUNK;
    for (int b = threadIdx.x; b < nbuck; b += SCAT_BLOCK) h[b] = 0;
    __syncthreads();
    // phase A: local histogram of this chunk
    for (int k = 0; k < SCAT_EPT; ++k) {
        long long e = base + k * SCAT_BLOCK + threadIdx.x;
        if (e < n_edges) atomicAdd(&h[rows[e] >> RPB_SHIFT], 1);
    }
    __syncthreads();
    // phase B: reserve one contiguous run per non-empty bucket
    for (int b = threadIdx.x; b < nbuck; b += SCAT_BLOCK)
        if (h[b]) cur[b] = atomicAdd(&gcursor[b], h[b]);
    __syncthreads();
    // phase C: place records; writes within a bucket run are contiguous
    for (int k = 0; k < SCAT_EPT; ++k) {
        long long e = base + k * SCAT_BLOCK + threadIdx.x;
        if (e < n_edges) {
            int r = rows[e];
            int pos = atomicAdd(&cur[r >> RPB_SHIFT], 1);
            int2 rec;
            rec.x = ((r & (RPB - 1)) << COL_BITS) | cols[e];
            rec.y = __float_as_int(vals[e]);
            edges[pos] = rec;
        }
    }
}

// ---------- pass 3: per-bucket LDS accumulate + coalesced writeout ----------
__global__ void k_baccum(const int* __restrict__ starts, const int2* __restrict__ edges,
                         const float* __restrict__ feat, float* __restrict__ out,
                         int n_nodes) {
    __shared__ float acc[RPB * NDIM];   // 16 KB
    int b = blockIdx.x;
    int start = starts[b];
    int end   = starts[b + 1];
    for (int i = threadIdx.x; i < RPB * NDIM; i += blockDim.x) acc[i] = 0.f;
    __syncthreads();

    int g = threadIdx.x >> 5;   // 8 edge-groups of 32 lanes
    int d = threadIdx.x & 31;
    int i = start + g;
    for (; i + 8 < end; i += 16) {      // 2 edges/group/iter for ILP
        int2 r0 = edges[i];
        int2 r1 = edges[i + 8];
        float f0 = feat[(long long)(r0.x & ((1 << COL_BITS) - 1)) * NDIM + d];
        float f1 = feat[(long long)(r1.x & ((1 << COL_BITS) - 1)) * NDIM + d];
        atomicAdd(&acc[((r0.x >> COL_BITS) << 5) + d], __int_as_float(r0.y) * f0);
        atomicAdd(&acc[((r1.x >> COL_BITS) << 5) + d], __int_as_float(r1.y) * f1);
    }
    for (; i < end; i += 8) {
        int2 r0 = edges[i];
        float f0 = feat[(long long)(r0.x & ((1 << COL_BITS) - 1)) * NDIM + d];
        atomicAdd(&acc[((r0.x >> COL_BITS) << 5) + d], __int_as_float(r0.y) * f0);
    }
    __syncthreads();

    long long row0 = (long long)b << RPB_SHIFT;
    int nrows = n_nodes - (int)row0;
    if (nrows > RPB) nrows = RPB;
    for (int j = threadIdx.x; j < nrows * NDIM; j += blockDim.x)
        out[row0 * NDIM + j] = acc[j];
}

// ---------- fallback: direct atomic scatter (round-1) ----------
__global__ void gc_scatter_atomic(const int* __restrict__ rows, const int* __restrict__ cols,
                                  const float* __restrict__ vals, const float* __restrict__ feat,
                                  float* __restrict__ out, int n_edges) {
    long long gid = (long long)blockIdx.x * blockDim.x + threadIdx.x;
    int e = (int)(gid >> 5);
    int d = (int)(gid & 31);
    if (e >= n_edges) return;
    float f = feat[(long long)cols[e] * NDIM + d];
    atomicAdd(&out[(long long)rows[e] * NDIM + d], vals[e] * f);
}

static inline size_t align_up(size_t x, size_t a) { return (x + a - 1) & ~(a - 1); }

extern "C" void kernel_launch(void* const* d_in, const int* in_sizes, int n_in,
                              void* d_out, int out_size, void* d_ws, size_t ws_size,
                              hipStream_t stream) {
    const int*   rows = (const int*)d_in[0];
    const int*   cols = (const int*)d_in[1];
    const float* vals = (const float*)d_in[2];
    const float* feat = (const float*)d_in[3];
    float*       out  = (float*)d_out;

    const int n_edges = in_sizes[0];
    const int n_nodes = in_sizes[3] / NDIM;
    const int nbuck   = (n_nodes + RPB - 1) >> RPB_SHIFT;

    // workspace layout: ghist[MAXB] | starts[MAXB+1] | cursor[MAXB] | edges[E]
    size_t hist_b  = align_up(MAXB * sizeof(int), 256);
    size_t start_b = align_up((MAXB + 1) * sizeof(int), 256);
    size_t cur_b   = align_up(MAXB * sizeof(int), 256);
    size_t edge_b  = (size_t)n_edges * sizeof(int2);
    size_t need = hist_b + start_b + cur_b + edge_b;

    if (ws_size < need || nbuck > MAXB || n_nodes > (1 << COL_BITS)) {
        hipMemsetAsync(out, 0, (size_t)out_size * sizeof(float), stream);
        long long total = (long long)n_edges * NDIM;
        unsigned nblock = (unsigned)((total + 255) / 256);
        gc_scatter_atomic<<<nblock, 256, 0, stream>>>(rows, cols, vals, feat, out, n_edges);
        return;
    }

    char* w = (char*)d_ws;
    int*  ghist  = (int*)w;
    int*  starts = (int*)(w + hist_b);
    int*  cursor = (int*)(w + hist_b + start_b);
    int2* edges  = (int2*)(w + hist_b + start_b + cur_b);

    hipMemsetAsync(ghist, 0, (size_t)nbuck * sizeof(int), stream);

    k_bhist<<<256, 256, 0, stream>>>(rows, ghist, n_edges, nbuck);
    k_bscan<<<1, MAXB, 0, stream>>>(ghist, starts, cursor, nbuck);
    int nchunks = (n_edges + SCAT_CHUNK - 1) / SCAT_CHUNK;
    k_bscatter<<<nchunks, SCAT_BLOCK, 0, stream>>>(rows, cols, vals, cursor, edges,
                                                   n_edges, nbuck);
    k_baccum<<<nbuck, 256, 0, stream>>>(starts, edges, feat, out, n_nodes);
}

// Round 4
// 394.683 us; speedup vs baseline: 1.0170x; 1.0170x over previous
//
#include <hip/hip_runtime.h>

#define NDIM 32
#define RPB 128            // rows per bucket
#define RPB_SHIFT 7
#define MAXB 1024          // max buckets supported (N <= 131072)
#define COL_BITS 17
#define SCAT_EPT 32        // edges per thread in scatter
#define SCAT_BLOCK 256
#define SCAT_CHUNK (SCAT_EPT * SCAT_BLOCK)   // 8192
#define ACC_BLOCK 1024
#define ACC_GROUPS (ACC_BLOCK / 32)          // 32 edge-groups per block

// ---------- pass 0: global bucket histogram (per-WG LDS hist, merged) ----------
__global__ void k_bhist(const int* __restrict__ rows, int* __restrict__ ghist,
                        int n_edges, int nbuck) {
    __shared__ int h[MAXB];
    for (int b = threadIdx.x; b < nbuck; b += blockDim.x) h[b] = 0;
    __syncthreads();
    int stride = gridDim.x * blockDim.x;
    for (int e = blockIdx.x * blockDim.x + threadIdx.x; e < n_edges; e += stride)
        atomicAdd(&h[rows[e] >> RPB_SHIFT], 1);
    __syncthreads();
    for (int b = threadIdx.x; b < nbuck; b += blockDim.x)
        if (h[b]) atomicAdd(&ghist[b], h[b]);
}

// ---------- pass 1: exclusive scan of bucket counts (1 WG, nbuck <= 1024) ----------
__global__ void k_bscan(const int* __restrict__ ghist, int* __restrict__ starts,
                        int* __restrict__ cursor, int nbuck) {
    __shared__ int lds[MAXB];
    int t = threadIdx.x;
    int v = (t < nbuck) ? ghist[t] : 0;
    lds[t] = v;
    __syncthreads();
    for (int off = 1; off < MAXB; off <<= 1) {
        int x = (t >= off) ? lds[t - off] : 0;
        __syncthreads();
        if (t >= off) lds[t] += x;
        __syncthreads();
    }
    int excl = lds[t] - v;
    if (t < nbuck) { starts[t] = excl; cursor[t] = excl; }
    if (t == nbuck - 1) starts[nbuck] = lds[t];
}

// ---------- pass 2: chunked rank-and-place into bucket order ----------
__global__ void k_bscatter(const int* __restrict__ rows, const int* __restrict__ cols,
                           const float* __restrict__ vals, int* __restrict__ gcursor,
                           int2* __restrict__ edges, int n_edges, int nbuck) {
    __shared__ int h[MAXB];
    __shared__ int cur[MAXB];
    long long base = (long long)blockIdx.x * SCAT_CHUNK;
    for (int b = threadIdx.x; b < nbuck; b += SCAT_BLOCK) h[b] = 0;
    __syncthreads();
    // phase A: local histogram of this chunk
    for (int k = 0; k < SCAT_EPT; ++k) {
        long long e = base + k * SCAT_BLOCK + threadIdx.x;
        if (e < n_edges) atomicAdd(&h[rows[e] >> RPB_SHIFT], 1);
    }
    __syncthreads();
    // phase B: reserve one contiguous run per non-empty bucket
    for (int b = threadIdx.x; b < nbuck; b += SCAT_BLOCK)
        if (h[b]) cur[b] = atomicAdd(&gcursor[b], h[b]);
    __syncthreads();
    // phase C: place records; writes within a bucket run are contiguous
    for (int k = 0; k < SCAT_EPT; ++k) {
        long long e = base + k * SCAT_BLOCK + threadIdx.x;
        if (e < n_edges) {
            int r = rows[e];
            int pos = atomicAdd(&cur[r >> RPB_SHIFT], 1);
            int2 rec;
            rec.x = ((r & (RPB - 1)) << COL_BITS) | cols[e];
            rec.y = __float_as_int(vals[e]);
            edges[pos] = rec;
        }
    }
}

// ---------- pass 3: per-bucket LDS accumulate, 1024 threads, 4-deep ILP ----------
__global__ __launch_bounds__(ACC_BLOCK)
void k_baccum(const int* __restrict__ starts, const int2* __restrict__ edges,
              const float* __restrict__ feat, float* __restrict__ out,
              int n_nodes) {
    __shared__ float acc[RPB * NDIM];   // 16 KB
    int b = blockIdx.x;
    int start = starts[b];
    int end   = starts[b + 1];
    for (int i = threadIdx.x; i < RPB * NDIM; i += ACC_BLOCK) acc[i] = 0.f;
    __syncthreads();

    const int CMASK = (1 << COL_BITS) - 1;
    int g = threadIdx.x >> 5;   // 32 edge-groups of 32 lanes
    int d = threadIdx.x & 31;
    int i = start + g;
    // 4 independent gathers in flight per group
    for (; i + 3 * ACC_GROUPS < end; i += 4 * ACC_GROUPS) {
        int2 r0 = edges[i];
        int2 r1 = edges[i + ACC_GROUPS];
        int2 r2 = edges[i + 2 * ACC_GROUPS];
        int2 r3 = edges[i + 3 * ACC_GROUPS];
        float f0 = feat[(long long)(r0.x & CMASK) * NDIM + d];
        float f1 = feat[(long long)(r1.x & CMASK) * NDIM + d];
        float f2 = feat[(long long)(r2.x & CMASK) * NDIM + d];
        float f3 = feat[(long long)(r3.x & CMASK) * NDIM + d];
        atomicAdd(&acc[((r0.x >> COL_BITS) << 5) + d], __int_as_float(r0.y) * f0);
        atomicAdd(&acc[((r1.x >> COL_BITS) << 5) + d], __int_as_float(r1.y) * f1);
        atomicAdd(&acc[((r2.x >> COL_BITS) << 5) + d], __int_as_float(r2.y) * f2);
        atomicAdd(&acc[((r3.x >> COL_BITS) << 5) + d], __int_as_float(r3.y) * f3);
    }
    for (; i < end; i += ACC_GROUPS) {
        int2 r0 = edges[i];
        float f0 = feat[(long long)(r0.x & CMASK) * NDIM + d];
        atomicAdd(&acc[((r0.x >> COL_BITS) << 5) + d], __int_as_float(r0.y) * f0);
    }
    __syncthreads();

    long long row0 = (long long)b << RPB_SHIFT;
    int nrows = n_nodes - (int)row0;
    if (nrows > RPB) nrows = RPB;
    float* op = out + row0 * NDIM;
    for (int j = threadIdx.x; j < nrows * NDIM; j += ACC_BLOCK)
        op[j] = acc[j];
}

// ---------- fallback: direct atomic scatter (round-1) ----------
__global__ void gc_scatter_atomic(const int* __restrict__ rows, const int* __restrict__ cols,
                                  const float* __restrict__ vals, const float* __restrict__ feat,
                                  float* __restrict__ out, int n_edges) {
    long long gid = (long long)blockIdx.x * blockDim.x + threadIdx.x;
    int e = (int)(gid >> 5);
    int d = (int)(gid & 31);
    if (e >= n_edges) return;
    float f = feat[(long long)cols[e] * NDIM + d];
    atomicAdd(&out[(long long)rows[e] * NDIM + d], vals[e] * f);
}

static inline size_t align_up(size_t x, size_t a) { return (x + a - 1) & ~(a - 1); }

extern "C" void kernel_launch(void* const* d_in, const int* in_sizes, int n_in,
                              void* d_out, int out_size, void* d_ws, size_t ws_size,
                              hipStream_t stream) {
    const int*   rows = (const int*)d_in[0];
    const int*   cols = (const int*)d_in[1];
    const float* vals = (const float*)d_in[2];
    const float* feat = (const float*)d_in[3];
    float*       out  = (float*)d_out;

    const int n_edges = in_sizes[0];
    const int n_nodes = in_sizes[3] / NDIM;
    const int nbuck   = (n_nodes + RPB - 1) >> RPB_SHIFT;

    // workspace layout: ghist[MAXB] | starts[MAXB+1] | cursor[MAXB] | edges[E]
    size_t hist_b  = align_up(MAXB * sizeof(int), 256);
    size_t start_b = align_up((MAXB + 1) * sizeof(int), 256);
    size_t cur_b   = align_up(MAXB * sizeof(int), 256);
    size_t edge_b  = (size_t)n_edges * sizeof(int2);
    size_t need = hist_b + start_b + cur_b + edge_b;

    if (ws_size < need || nbuck > MAXB || n_nodes > (1 << COL_BITS)) {
        hipMemsetAsync(out, 0, (size_t)out_size * sizeof(float), stream);
        long long total = (long long)n_edges * NDIM;
        unsigned nblock = (unsigned)((total + 255) / 256);
        gc_scatter_atomic<<<nblock, 256, 0, stream>>>(rows, cols, vals, feat, out, n_edges);
        return;
    }

    char* w = (char*)d_ws;
    int*  ghist  = (int*)w;
    int*  starts = (int*)(w + hist_b);
    int*  cursor = (int*)(w + hist_b + start_b);
    int2* edges  = (int2*)(w + hist_b + start_b + cur_b);

    hipMemsetAsync(ghist, 0, (size_t)nbuck * sizeof(int), stream);

    k_bhist<<<256, 256, 0, stream>>>(rows, ghist, n_edges, nbuck);
    k_bscan<<<1, MAXB, 0, stream>>>(ghist, starts, cursor, nbuck);
    int nchunks = (n_edges + SCAT_CHUNK - 1) / SCAT_CHUNK;
    k_bscatter<<<nchunks, SCAT_BLOCK, 0, stream>>>(rows, cols, vals, cursor, edges,
                                                   n_edges, nbuck);
    k_baccum<<<nbuck, ACC_BLOCK, 0, stream>>>(starts, edges, feat, out, n_nodes);
}